// Round 22
// baseline (104.353 us; speedup 1.0000x reference)
//
#include <hip/hip_runtime.h>

#define SEQ_N 1024
#define BATCH 64
#define KSL   16           // epoch length (steps between barriers)
#define DELTA 80           // wave delay (63 lane skew + LAG 17)
#define RINGN 80           // 64 slots + 16 mirror (wrap-free batched reads)
#define PAD_F 304          // front pad: max off = 3*80+63 = 303
#define PAD_B 320          // back pad: max yp prefetch index 831
#define NPAIR 512          // columns per sweep (half matrix)
#define SYN   (PAD_F + NPAIR + PAD_B)

// Wave-wide shift-up-by-1 in one instruction (DPP wave_shr:1, ctrl 0x138).
__device__ __forceinline__ float wave_shr1(float v, float fill) {
    return __int_as_float(__builtin_amdgcn_update_dpp(
        __float_as_int(fill), __float_as_int(v), 0x138, 0xF, 0xF, false));
}

// CO-SCHEDULED bidirectional DTW: one 512-thread block per matrix.
// Waves 0-3 (group F) run the forward sweep over cols [0,512); waves 4-7
// (group B) run the backward sweep (reversed seqs, P = G+d / Q = P+d carry,
// R19-verified) over cols [512,1024). Waves map to SIMDs round-robin, so
// each SIMD hosts one F-wave + one B-wave with INDEPENDENT dependency
// chains: R13 measured 75% per-SIMD issue occupancy in this regime vs 46%
// at 1 wave/SIMD -- the stall that capped every prior variant.
// Both groups run the IDENTICAL 51-epoch schedule; the __syncthreads sits
// OUTSIDE the wave-uniform group branch (equal barrier counts).
// Stitch is fused in-block: F-col / P-col / x go to LDS, then
//   D = min_i[ F[i,511] + min(P[i,512], P[i+1,512] + |x[i+1]-y[512]|) ]
// (R15/R19 HW-verified formula), one block-level min-reduce, dists[b].
//
// Epoch/ring machinery = R8-verified KSL=16/DELTA=80 geometry: LAG=17;
// RAW >=1 barrier; WAR slot reuse (p+64, 4 epochs) >=2 barriers after last
// read; rbase=(16E-17)&63 in {47,63,15,31}, only 63 wraps into mirror
// [64..79] written by mm==0 producer epochs.
// Seeds at (e0,k2=0,th==0): F: up=0 -> D[0,0]=d (then diag->INF);
// B: upP=0 -> P'[0,0]=d' (upQ INF naturally).
__global__ __launch_bounds__(512, 1) void dtw_kernel(const float* __restrict__ x,
                                                     const float* __restrict__ y,
                                                     float* __restrict__ dists) {
    __shared__ float  syF[SYN];
    __shared__ float  syB[SYN];
    __shared__ float  ringF[3][RINGN];
    __shared__ float2 ringB[3][RINGN];
    __shared__ float  stX[SEQ_N];
    __shared__ float  red8[8];

    const int b   = blockIdx.x;
    const int tid = threadIdx.x;
    const bool gF = (tid < 256);     // group: F = waves 0-3, B = waves 4-7
    const int th  = tid & 255;       // thread id within group
    const int w   = th >> 6;         // wave id within group, 0..3
    const int l   = tid & 63;
    const float INF = 3.0e37f;
    const int  off = w * DELTA + l;
    const bool is_ring_l0 = (l == 0) && (w > 0);
    const bool is_seed = (th == 0);
    const int  r0 = w * 256 + l * 4;

    // zero both y-buffers (pads + data), then stage
    for (int i = tid; i < SYN; i += 512) { syF[i] = 0.0f; syB[i] = 0.0f; }
    __syncthreads();
    if (gF) {
        if (th < NPAIR / 4)
            ((float4*)(syF + PAD_F))[th] = ((const float4*)(y + b * SEQ_N))[th];
    } else {
        if (th < NPAIR / 4) {   // y'[q] = y[1023-q]
            const float4 v = *((const float4*)(y + b * SEQ_N + 1020 - 4 * th));
            ((float4*)(syB + PAD_F))[th] = make_float4(v.w, v.z, v.y, v.x);
        }
    }
    // x fragments; F group stashes x into LDS for the stitch phase
    float xr0, xr1, xr2, xr3;
    if (gF) {
        const float4 v = *((const float4*)(x + b * SEQ_N + r0));
        xr0 = v.x; xr1 = v.y; xr2 = v.z; xr3 = v.w;
        stX[r0] = xr0; stX[r0 + 1] = xr1; stX[r0 + 2] = xr2; stX[r0 + 3] = xr3;
    } else {
        const float4 v = *((const float4*)(x + b * SEQ_N + 1020 - r0));
        xr0 = v.w; xr1 = v.z; xr2 = v.y; xr3 = v.x;
    }
    __syncthreads();

    const float* const yp = (gF ? syF : syB) + PAD_F - off;

    // F state
    float c0 = INF, c1 = INF, c2 = INF, c3 = INF;
    float diag_top = INF, bottom = INF;
    // B state
    float cP0 = INF, cP1 = INF, cP2 = INF, cP3 = INF;
    float cQ0 = INF, cQ1 = INF, cQ2 = INF, cQ3 = INF;
    float diag_Q = INF, botP = INF, botQ = INF;
    // shared register arrays (both groups use the same names -> one allocation)
    float yA[KSL], yB2[KSL], rbP[KSL], rbQ[KSL], btP[KSL], btQ[KSL];

    #pragma unroll
    for (int k = 0; k < KSL; ++k) yA[k] = yp[k];

#define EPOCH(MASKED, FIRST, S0, YU, YF2)                                    \
  {                                                                          \
    __syncthreads();                                                         \
    if (gF) {                                                                \
      if (w > 0) {                                                           \
        int rbase = ((S0) & 63) + 47; if (rbase >= 64) rbase -= 64;          \
        const float* rp = ringF[w - 1] + rbase;                              \
        _Pragma("unroll")                                                    \
        for (int k2 = 0; k2 < KSL; ++k2) rbP[k2] = rp[k2];                   \
      } else {                                                               \
        _Pragma("unroll")                                                    \
        for (int k2 = 0; k2 < KSL; ++k2) rbP[k2] = INF;                      \
      }                                                                      \
      _Pragma("unroll")                                                      \
      for (int k2 = 0; k2 < KSL; ++k2) YF2[k2] = yp[(S0) + KSL + k2];        \
      _Pragma("unroll")                                                      \
      for (int k2 = 0; k2 < KSL; ++k2) {                                     \
        const float up_dpp = wave_shr1(bottom, INF);                         \
        float upv = is_ring_l0 ? rbP[k2] : up_dpp;                           \
        if ((FIRST) && k2 == 0 && is_seed) upv = 0.0f;                       \
        const float yj = YU[k2];                                             \
        bool act = true;                                                     \
        if (MASKED) act = ((unsigned)((S0) + k2 - off) < (unsigned)NPAIR);   \
        if (act) {                                                           \
          const float d0 = xr0 - yj, d1 = xr1 - yj,                          \
                      d2 = xr2 - yj, d3 = xr3 - yj;                          \
          const float t0 = diag_top + fabsf(d0);                             \
          const float t1 = c0 + fabsf(d1);                                   \
          const float t2 = c1 + fabsf(d2);                                   \
          const float t3 = c2 + fabsf(d3);                                   \
          float v = upv;                                                     \
          v = fminf(fminf(t0, c0), v) + fabsf(d0); c0 = v;                   \
          v = fminf(fminf(t1, c1), v) + fabsf(d1); c1 = v;                   \
          v = fminf(fminf(t2, c2), v) + fabsf(d2); c2 = v;                   \
          v = fminf(fminf(t3, c3), v) + fabsf(d3); c3 = v;                   \
          diag_top = upv; bottom = v;                                        \
        }                                                                    \
        if ((FIRST) && k2 == 0 && is_seed) diag_top = INF;                   \
        btP[k2] = bottom;                                                    \
      }                                                                      \
      if (w < 3 && l == 63) {                                                \
        const int mm = (S0) & 63;                                            \
        float* wp = ringF[w] + mm;                                           \
        _Pragma("unroll")                                                    \
        for (int k2 = 0; k2 < KSL; ++k2) wp[k2] = btP[k2];                   \
        if (mm == 0) {                                                       \
          _Pragma("unroll")                                                  \
          for (int k2 = 0; k2 < KSL; ++k2) ringF[w][64 + k2] = btP[k2];      \
        }                                                                    \
      }                                                                      \
    } else {                                                                 \
      if (w > 0) {                                                           \
        int rbase = ((S0) & 63) + 47; if (rbase >= 64) rbase -= 64;          \
        const float2* rp = ringB[w - 1] + rbase;                             \
        _Pragma("unroll")                                                    \
        for (int k2 = 0; k2 < KSL; ++k2) { rbP[k2] = rp[k2].x; rbQ[k2] = rp[k2].y; } \
      } else {                                                               \
        _Pragma("unroll")                                                    \
        for (int k2 = 0; k2 < KSL; ++k2) { rbP[k2] = INF; rbQ[k2] = INF; }   \
      }                                                                      \
      _Pragma("unroll")                                                      \
      for (int k2 = 0; k2 < KSL; ++k2) YF2[k2] = yp[(S0) + KSL + k2];        \
      _Pragma("unroll")                                                      \
      for (int k2 = 0; k2 < KSL; ++k2) {                                     \
        float upP = wave_shr1(botP, INF);                                    \
        float upQ = wave_shr1(botQ, INF);                                    \
        if (is_ring_l0) { upP = rbP[k2]; upQ = rbQ[k2]; }                    \
        if ((FIRST) && k2 == 0 && is_seed) upP = 0.0f;  /* P'[0,0]=d' */     \
        const float yj = YU[k2];                                             \
        bool act = true;                                                     \
        if (MASKED) act = ((unsigned)((S0) + k2 - off) < (unsigned)NPAIR);   \
        if (act) {                                                           \
          const float f0 = xr0 - yj, f1 = xr1 - yj,                          \
                      f2 = xr2 - yj, f3 = xr3 - yj;                          \
          const float n0 = fminf(fminf(diag_Q, cP0), upP) + fabsf(f0);       \
          const float n1 = fminf(fminf(cQ0, cP1), n0) + fabsf(f1);           \
          const float n2 = fminf(fminf(cQ1, cP2), n1) + fabsf(f2);           \
          const float n3 = fminf(fminf(cQ2, cP3), n2) + fabsf(f3);           \
          cQ0 = n0 + fabsf(f0); cQ1 = n1 + fabsf(f1);                        \
          cQ2 = n2 + fabsf(f2); cQ3 = n3 + fabsf(f3);                        \
          cP0 = n0; cP1 = n1; cP2 = n2; cP3 = n3;                            \
          diag_Q = upQ; botP = n3; botQ = cQ3;                               \
        }                                                                    \
        btP[k2] = botP; btQ[k2] = botQ;                                      \
      }                                                                      \
      if (w < 3 && l == 63) {                                                \
        const int mm = (S0) & 63;                                            \
        float2* wp = ringB[w] + mm;                                          \
        _Pragma("unroll")                                                    \
        for (int k2 = 0; k2 < KSL; ++k2) wp[k2] = make_float2(btP[k2], btQ[k2]); \
        if (mm == 0) {                                                       \
          _Pragma("unroll")                                                  \
          for (int k2 = 0; k2 < KSL; ++k2)                                   \
            ringB[w][64 + k2] = make_float2(btP[k2], btQ[k2]);               \
        }                                                                    \
      }                                                                      \
    }                                                                        \
  }

    // 51 epochs of 16 steps (R19-verified schedule; last active step 814)
    EPOCH(true, true, 0, yA, yB2);                      // e0 (corner seeds)
    int s0 = 16;
    for (int it = 0; it < 9; ++it) {                    // e1..e18 ramp-up
        EPOCH(true, false, s0, yB2, yA);
        EPOCH(true, false, s0 + 16, yA, yB2);
        s0 += 32;
    }
    for (int it = 0; it < 6; ++it) {                    // e19..e30 steady
        EPOCH(false, false, s0, yB2, yA);
        EPOCH(false, false, s0 + 16, yA, yB2);
        s0 += 32;
    }
    EPOCH(false, false, s0, yB2, yA); s0 += 16;         // e31
    for (int it = 0; it < 9; ++it) {                    // e32..e49 ramp-down
        EPOCH(true, false, s0, yA, yB2);
        EPOCH(true, false, s0 + 16, yB2, yA);
        s0 += 32;
    }
    EPOCH(true, false, s0, yA, yB2);                    // e50
#undef EPOCH

    // ---- fused in-block stitch ----
    const float y_cut = syB[PAD_F + 511];   // = y[512] (syB untouched since staging)
    __syncthreads();                        // all sweep LDS reads complete
    if (gF) {                               // F-col -> syF[0..1023]
        syF[r0] = c0; syF[r0 + 1] = c1; syF[r0 + 2] = c2; syF[r0 + 3] = c3;
    } else {                                // P-col -> syB[i] = P[i,512]
        syB[1023 - r0] = cP0; syB[1022 - r0] = cP1;
        syB[1021 - r0] = cP2; syB[1020 - r0] = cP3;
    }
    __syncthreads();
    float m = INF;
    #pragma unroll
    for (int k = 0; k < 2; ++k) {
        const int i = 2 * tid + k;
        const float alt = (i < 1023) ? syB[i + 1] + fabsf(stX[i + 1] - y_cut) : INF;
        m = fminf(m, syF[i] + fminf(syB[i], alt));
    }
    #pragma unroll
    for (int o = 32; o > 0; o >>= 1) m = fminf(m, __shfl_down(m, o));
    if (l == 0) red8[tid >> 6] = m;
    __syncthreads();
    if (tid == 0) {
        float r = red8[0];
        #pragma unroll
        for (int i = 1; i < 8; ++i) r = fminf(r, red8[i]);
        dists[b] = r * (1.0f / (2.0f * (float)SEQ_N));
    }
}

// Mean over the 64 per-batch distances -> single float output.
__global__ void dtw_reduce_kernel(const float* __restrict__ dists,
                                  float* __restrict__ out) {
    float v = dists[threadIdx.x] * (1.0f / (float)BATCH);
    #pragma unroll
    for (int o = 32; o > 0; o >>= 1) v += __shfl_down(v, o);
    if (threadIdx.x == 0) out[0] = v;
}

extern "C" void kernel_launch(void* const* d_in, const int* in_sizes, int n_in,
                              void* d_out, int out_size, void* d_ws, size_t ws_size,
                              hipStream_t stream) {
    const float* x = (const float*)d_in[0];
    const float* y = (const float*)d_in[1];
    float* out = (float*)d_out;
    float* dists = (float*)d_ws;  // 64 floats of scratch

    dtw_kernel<<<BATCH, 512, 0, stream>>>(x, y, dists);
    dtw_reduce_kernel<<<1, BATCH, 0, stream>>>(dists, out);
}

// Round 23
// 82.965 us; speedup vs baseline: 1.2578x; 1.2578x over previous
//
#include <hip/hip_runtime.h>

#define SEQ_N 1024
#define BATCH 64
#define NW    4            // waves per block
#define KSL   16           // epoch length (steps between barriers)
#define DELTA 80           // wave delay (63 lane skew + LAG 17)
#define RINGN 80           // 64 slots + 16 mirror (wrap-free batched reads)
#define PAD_F 304          // front pad: max off = 3*80+63 = 303
#define PAD_B 320          // back pad: max yp index 831
#define NPAIR 512          // columns per sweep (half matrix)
#define SYN   (PAD_F + NPAIR + PAD_B)

// Wave-wide shift-up-by-1 in one instruction (DPP wave_shr:1, ctrl 0x138).
// bound_ctrl=false -> lane 0 takes `fill` = top-row boundary for free.
__device__ __forceinline__ float wave_shr1(float v, float fill) {
    return __int_as_float(__builtin_amdgcn_update_dpp(
        __float_as_int(fill), __float_as_int(v), 0x138, 0xF, 0xF, false));
}

// SPLIT-BLOCK bidirectional DTW — best verified configuration (R19: 83.4us).
// Blocks 0..63: forward F over cols [0,512). Blocks 64..127: backward over
// cols [512,1024) on reversed sequences, carrying P = G + d AND Q = P + d:
//   P_r = min3( Qold[r-1], Pold[r], Pnew[r-1] ) + |f_r|;  Q_r = P_r + |f_r|
// (diag needs NO neighbor-diff carry). Exchange = (botP,botQ) via 2 DPPs /
// float2 ring. Seed: upP=0 at (e0,k2=0,tid0) -> P'[0,0]=d'.
// Stitch (HW-verified): D = min_i[F[i] + min(P[i], P[i+1]+|x[i+1]-y512|)].
//
// Epoch/ring machinery = R8-verified KSL=16/DELTA=80 geometry:
//   LAG=17; RAW: epoch-E head reads p in [16E-17,16E-2] (epochs E-2/E-1);
//   WAR: slot p reused at p+64, >=2 barriers after last read;
//   Wrap: rbase=(16E-17)&63 in {47,63,15,31}; only 63 wraps into mirror
//   [64..79], written by the mm==0 producer epochs.
//
// Structural floor note: all measured variants obey
//   wall/step ~= 2cy*instr + chain-stall, per-SIMD issue ~46% @1 wave/SIMD;
// more waves/SIMD either halves CUs (R13) or couples via barrier (R22).
// 816 steps x ~230cy = 78us sweep + 5us stitch/reduce is this family's floor.
__global__ __launch_bounds__(256, 1) void dtw_sweep_kernel(const float* __restrict__ x,
                                                           const float* __restrict__ y,
                                                           float* __restrict__ wsF,
                                                           float* __restrict__ wsP) {
    __shared__ float  sy_raw[SYN];
    __shared__ float  ringF[NW - 1][RINGN];
    __shared__ float2 ringB[NW - 1][RINGN];

    const int bid = blockIdx.x;
    const int dir = bid >> 6;        // 0 = forward, 1 = backward
    const int b   = bid & 63;
    const int tid = threadIdx.x;
    const int w   = tid >> 6;
    const int l   = tid & 63;
    const float INF = 3.0e37f;
    const int  off = w * DELTA + l;
    const bool is_ring_l0 = (l == 0) && (w > 0);
    const bool is_seed = (tid == 0);
    const int  r0 = w * 256 + l * 4;

    // zero pads
    for (int i = tid; i < PAD_F; i += 256) sy_raw[i] = 0.0f;
    for (int i = tid; i < PAD_B; i += 256) sy_raw[PAD_F + NPAIR + i] = 0.0f;
    // stage y columns: fwd y[0..511]; bwd y'[q] = y[1023-q]
    if (tid < NPAIR / 4) {
        if (dir == 0) {
            ((float4*)(sy_raw + PAD_F))[tid] = ((const float4*)(y + b * SEQ_N))[tid];
        } else {
            const float4 v = *((const float4*)(y + b * SEQ_N + 1020 - 4 * tid));
            ((float4*)(sy_raw + PAD_F))[tid] = make_float4(v.w, v.z, v.y, v.x);
        }
    }
    // x fragment: fwd rows r0..r0+3; bwd x'[p] = x[1023-p]
    float xr0, xr1, xr2, xr3;
    if (dir == 0) {
        const float4 v = *((const float4*)(x + b * SEQ_N + r0));
        xr0 = v.x; xr1 = v.y; xr2 = v.z; xr3 = v.w;
    } else {
        const float4 v = *((const float4*)(x + b * SEQ_N + 1020 - r0));
        xr0 = v.w; xr1 = v.z; xr2 = v.y; xr3 = v.x;
    }
    __syncthreads();

    const float* const yp = sy_raw + PAD_F - off;   // yp[s] == y-col for step s

    if (dir == 0) {
        // ---------------- FORWARD (R8/R12-verified machinery) ----------------
        float c0 = INF, c1 = INF, c2 = INF, c3 = INF;
        float diag_top = INF, bottom = INF;
        float yA[KSL], yB[KSL], rb[KSL], bt[KSL];
        #pragma unroll
        for (int k = 0; k < KSL; ++k) yA[k] = yp[k];

#define FEPOCH(MASKED, FIRST, S0, YU, YF)                                    \
  {                                                                          \
    __syncthreads();                                                         \
    if (w > 0) {                                                             \
      int rbase = ((S0) & 63) + 47; if (rbase >= 64) rbase -= 64;            \
      const float* rp = ringF[w - 1] + rbase;                                \
      _Pragma("unroll")                                                      \
      for (int k2 = 0; k2 < KSL; ++k2) rb[k2] = rp[k2];                      \
    } else {                                                                 \
      _Pragma("unroll")                                                      \
      for (int k2 = 0; k2 < KSL; ++k2) rb[k2] = INF;                         \
    }                                                                        \
    _Pragma("unroll")                                                        \
    for (int k2 = 0; k2 < KSL; ++k2) YF[k2] = yp[(S0) + KSL + k2];           \
    _Pragma("unroll")                                                        \
    for (int k2 = 0; k2 < KSL; ++k2) {                                       \
      const float up_dpp = wave_shr1(bottom, INF);                           \
      float upv = is_ring_l0 ? rb[k2] : up_dpp;                              \
      if ((FIRST) && k2 == 0 && is_seed) upv = 0.0f;                         \
      const float yj = YU[k2];                                               \
      bool act = true;                                                       \
      if (MASKED) act = ((unsigned)((S0) + k2 - off) < (unsigned)NPAIR);     \
      if (act) {                                                             \
        const float d0 = xr0 - yj, d1 = xr1 - yj,                            \
                    d2 = xr2 - yj, d3 = xr3 - yj;                            \
        const float t0 = diag_top + fabsf(d0);                               \
        const float t1 = c0 + fabsf(d1);                                     \
        const float t2 = c1 + fabsf(d2);                                     \
        const float t3 = c2 + fabsf(d3);                                     \
        float v = upv;                                                       \
        v = fminf(fminf(t0, c0), v) + fabsf(d0); c0 = v;                     \
        v = fminf(fminf(t1, c1), v) + fabsf(d1); c1 = v;                     \
        v = fminf(fminf(t2, c2), v) + fabsf(d2); c2 = v;                     \
        v = fminf(fminf(t3, c3), v) + fabsf(d3); c3 = v;                     \
        diag_top = upv; bottom = v;                                          \
      }                                                                      \
      if ((FIRST) && k2 == 0 && is_seed) diag_top = INF;                     \
      bt[k2] = bottom;                                                       \
    }                                                                        \
    if (w < NW - 1 && l == 63) {                                             \
      const int mm = (S0) & 63;                                              \
      float* wp = ringF[w] + mm;                                             \
      _Pragma("unroll")                                                      \
      for (int k2 = 0; k2 < KSL; ++k2) wp[k2] = bt[k2];                      \
      if (mm == 0) {                                                         \
        _Pragma("unroll")                                                    \
        for (int k2 = 0; k2 < KSL; ++k2) ringF[w][64 + k2] = bt[k2];         \
      }                                                                      \
    }                                                                        \
  }
        FEPOCH(true, true, 0, yA, yB);
        int s0 = 16;
        for (int it = 0; it < 9; ++it) {                // e1..e18 ramp-up
            FEPOCH(true, false, s0, yB, yA);
            FEPOCH(true, false, s0 + 16, yA, yB);
            s0 += 32;
        }
        for (int it = 0; it < 6; ++it) {                // e19..e30 steady
            FEPOCH(false, false, s0, yB, yA);
            FEPOCH(false, false, s0 + 16, yA, yB);
            s0 += 32;
        }
        FEPOCH(false, false, s0, yB, yA); s0 += 16;     // e31
        for (int it = 0; it < 9; ++it) {                // e32..e49 ramp-down
            FEPOCH(true, false, s0, yA, yB);
            FEPOCH(true, false, s0 + 16, yB, yA);
            s0 += 32;
        }
        FEPOCH(true, false, s0, yA, yB);                // e50
#undef FEPOCH
        *((float4*)(wsF + b * SEQ_N + r0)) = make_float4(c0, c1, c2, c3);
    } else {
        // ---------------- BACKWARD, Q-carry (P = G + d, Q = P + d) ----------
        float cP0 = INF, cP1 = INF, cP2 = INF, cP3 = INF;
        float cQ0 = INF, cQ1 = INF, cQ2 = INF, cQ3 = INF;
        float diag_Q = INF, botP = INF, botQ = INF;
        float yA[KSL], yB[KSL];
        float2 rb2[KSL], bt2[KSL];
        #pragma unroll
        for (int k = 0; k < KSL; ++k) yA[k] = yp[k];

#define BEPOCH(MASKED, FIRST, S0, YU, YF)                                    \
  {                                                                          \
    __syncthreads();                                                         \
    if (w > 0) {                                                             \
      int rbase = ((S0) & 63) + 47; if (rbase >= 64) rbase -= 64;            \
      const float2* rp = ringB[w - 1] + rbase;                               \
      _Pragma("unroll")                                                      \
      for (int k2 = 0; k2 < KSL; ++k2) rb2[k2] = rp[k2];                     \
    } else {                                                                 \
      _Pragma("unroll")                                                      \
      for (int k2 = 0; k2 < KSL; ++k2) rb2[k2] = make_float2(INF, INF);      \
    }                                                                        \
    _Pragma("unroll")                                                        \
    for (int k2 = 0; k2 < KSL; ++k2) YF[k2] = yp[(S0) + KSL + k2];           \
    _Pragma("unroll")                                                        \
    for (int k2 = 0; k2 < KSL; ++k2) {                                       \
      float upP = wave_shr1(botP, INF);                                      \
      float upQ = wave_shr1(botQ, INF);                                      \
      if (is_ring_l0) { upP = rb2[k2].x; upQ = rb2[k2].y; }                  \
      if ((FIRST) && k2 == 0 && is_seed) upP = 0.0f;  /* P'[0,0] = d' */     \
      const float yj = YU[k2];                                               \
      bool act = true;                                                       \
      if (MASKED) act = ((unsigned)((S0) + k2 - off) < (unsigned)NPAIR);     \
      if (act) {                                                             \
        const float f0 = xr0 - yj, f1 = xr1 - yj,                            \
                    f2 = xr2 - yj, f3 = xr3 - yj;                            \
        const float n0 = fminf(fminf(diag_Q, cP0), upP) + fabsf(f0);         \
        const float n1 = fminf(fminf(cQ0, cP1), n0) + fabsf(f1);             \
        const float n2 = fminf(fminf(cQ1, cP2), n1) + fabsf(f2);             \
        const float n3 = fminf(fminf(cQ2, cP3), n2) + fabsf(f3);             \
        cQ0 = n0 + fabsf(f0); cQ1 = n1 + fabsf(f1);                          \
        cQ2 = n2 + fabsf(f2); cQ3 = n3 + fabsf(f3);                          \
        cP0 = n0; cP1 = n1; cP2 = n2; cP3 = n3;                              \
        diag_Q = upQ; botP = n3; botQ = cQ3;                                 \
      }                                                                      \
      bt2[k2] = make_float2(botP, botQ);                                     \
    }                                                                        \
    if (w < NW - 1 && l == 63) {                                             \
      const int mm = (S0) & 63;                                              \
      float2* wp = ringB[w] + mm;                                            \
      _Pragma("unroll")                                                      \
      for (int k2 = 0; k2 < KSL; ++k2) wp[k2] = bt2[k2];                     \
      if (mm == 0) {                                                         \
        _Pragma("unroll")                                                    \
        for (int k2 = 0; k2 < KSL; ++k2) ringB[w][64 + k2] = bt2[k2];        \
      }                                                                      \
    }                                                                        \
  }
        BEPOCH(true, true, 0, yA, yB);
        int s0 = 16;
        for (int it = 0; it < 9; ++it) {                // e1..e18 ramp-up
            BEPOCH(true, false, s0, yB, yA);
            BEPOCH(true, false, s0 + 16, yA, yB);
            s0 += 32;
        }
        for (int it = 0; it < 6; ++it) {                // e19..e30 steady
            BEPOCH(false, false, s0, yB, yA);
            BEPOCH(false, false, s0 + 16, yA, yB);
            s0 += 32;
        }
        BEPOCH(false, false, s0, yB, yA); s0 += 16;     // e31
        for (int it = 0; it < 9; ++it) {                // e32..e49 ramp-down
            BEPOCH(true, false, s0, yA, yB);
            BEPOCH(true, false, s0 + 16, yB, yA);
            s0 += 32;
        }
        BEPOCH(true, false, s0, yA, yB);                // e50
#undef BEPOCH
        // export P[i,512]: cPk holds P'[r0+k,511] = P[1023-(r0+k),512]
        *((float4*)(wsP + b * SEQ_N + 1020 - r0)) = make_float4(cP3, cP2, cP1, cP0);
    }
}

// Stitch: D[b] = min_i [ F[i] + min(P[i], P[i+1] + |x[i+1]-y[512]|) ] / 2048
__global__ void dtw_stitch_kernel(const float* __restrict__ x,
                                  const float* __restrict__ y,
                                  const float* __restrict__ wsF,
                                  const float* __restrict__ wsP,
                                  float* __restrict__ dists) {
    __shared__ float red[4];
    const int b = blockIdx.x, t = threadIdx.x;
    const float INF = 3.0e37f;
    const float y512 = y[b * SEQ_N + 512];
    const float4 Fv = ((const float4*)(wsF + b * SEQ_N))[t];
    const float4 Pv = ((const float4*)(wsP + b * SEQ_N))[t];
    const float Pn4 = (t < 255) ? wsP[b * SEQ_N + 4 * t + 4] : INF;
    const float F[4]  = {Fv.x, Fv.y, Fv.z, Fv.w};
    const float P[4]  = {Pv.x, Pv.y, Pv.z, Pv.w};
    const float Pn[4] = {Pv.y, Pv.z, Pv.w, Pn4};
    float m = INF;
    #pragma unroll
    for (int k = 0; k < 4; ++k) {
        const int i = 4 * t + k;
        const float xn = (i < 1023) ? x[b * SEQ_N + i + 1] : 0.f;
        const float alt = (i < 1023) ? Pn[k] + fabsf(xn - y512) : INF;
        m = fminf(m, F[k] + fminf(P[k], alt));
    }
    #pragma unroll
    for (int o = 32; o > 0; o >>= 1) m = fminf(m, __shfl_down(m, o));
    if ((t & 63) == 0) red[t >> 6] = m;
    __syncthreads();
    if (t == 0)
        dists[b] = fminf(fminf(red[0], red[1]), fminf(red[2], red[3]))
                   * (1.0f / (2.0f * (float)SEQ_N));
}

// Mean over the 64 per-batch distances -> single float output.
__global__ void dtw_reduce_kernel(const float* __restrict__ dists,
                                  float* __restrict__ out) {
    float v = dists[threadIdx.x] * (1.0f / (float)BATCH);
    #pragma unroll
    for (int o = 32; o > 0; o >>= 1) v += __shfl_down(v, o);
    if (threadIdx.x == 0) out[0] = v;
}

extern "C" void kernel_launch(void* const* d_in, const int* in_sizes, int n_in,
                              void* d_out, int out_size, void* d_ws, size_t ws_size,
                              hipStream_t stream) {
    const float* x = (const float*)d_in[0];
    const float* y = (const float*)d_in[1];
    float* out = (float*)d_out;
    float* wsF   = (float*)d_ws;                     // 64*1024 floats
    float* wsP   = wsF + BATCH * SEQ_N;              // 64*1024 floats
    float* dists = wsP + BATCH * SEQ_N;              // 64 floats

    dtw_sweep_kernel<<<2 * BATCH, 256, 0, stream>>>(x, y, wsF, wsP);
    dtw_stitch_kernel<<<BATCH, 256, 0, stream>>>(x, y, wsF, wsP, dists);
    dtw_reduce_kernel<<<1, BATCH, 0, stream>>>(dists, out);
}